// Round 5
// baseline (128.964 us; speedup 1.0000x reference)
//
#include <hip/hip_runtime.h>
#include <hip/hip_bf16.h>
#include <math.h>

#define Cch 64
#define Hh  256
#define Ww  256
#define HW  (Hh * Ww)

// ws layout (32-bit words)
#define WS_WA   0        // [4 g][3 s][64 lane][8 u32]  A-frags: hi(4) + lo(4)
#define WS_WGC  6144     // [4 g][16 o][9 k] f32 group-max weights
#define WS_WC2  6720     // [16][16] f32 conv2 center taps
#define WS_SC   6976     // [16] BN scale
#define WS_OFF  6992     // [16] BN offset (incl conv2 bias)

typedef __attribute__((ext_vector_type(8))) short bf16x8;
typedef __attribute__((ext_vector_type(4))) float f32x4;

__device__ __forceinline__ float mishf(float x) {
    float e  = __expf(fminf(x, 15.0f));
    float n  = 1.0f + e;
    float n2 = n * n;
    float t  = __fdividef(n2 - 1.0f, n2 + 1.0f);
    return x > 15.0f ? x : x * t;
}

__device__ __forceinline__ unsigned packbf(float a, float b) {
    unsigned short ua = __builtin_bit_cast(unsigned short, __float2bfloat16(a));
    unsigned short ub = __builtin_bit_cast(unsigned short, __float2bfloat16(b));
    return (unsigned)ua | ((unsigned)ub << 16);
}

// conv1 weight for (group g, output m, local-k k), k<96: k=6*cc+r,
// r<3 -> m_kh(kw=r), r>=3 -> m_kw(kh=r-3), channel c=g*16+cc
__device__ __forceinline__ float conv1_wval(const float* w1, int g, int m, int k) {
    int cc = k / 6, r = k % 6;
    int col = (r < 3) ? (36 + (g * 16 + cc) * 3 + r)
                      : (228 + (g * 16 + cc) * 3 + (r - 3));
    return w1[m * 420 + col];
}

__global__ __launch_bounds__(256) void prep_kernel(
    const float* __restrict__ w1, const float* __restrict__ w2,
    const float* __restrict__ b2,
    const float* __restrict__ gamma, const float* __restrict__ beta,
    const float* __restrict__ mean,  const float* __restrict__ var,
    float* __restrict__ ws)
{
    unsigned* wsu = (unsigned*)ws;
    const int tid = threadIdx.x;

    // A-fragments: lane holds A[m=lane&15][k=32s+(lane>>4)*8+j], hi/lo split
    for (int idx = tid; idx < 768; idx += 256) {
        int g = idx / 192, rem = idx % 192, s = rem / 64, lane = rem % 64;
        int m = lane & 15, half = lane >> 4;
        unsigned hi[4], lo[4];
        #pragma unroll
        for (int jp = 0; jp < 4; ++jp) {
            float hv[2], lv[2];
            #pragma unroll
            for (int e = 0; e < 2; ++e) {
                int k = 32 * s + half * 8 + jp * 2 + e;
                float v  = conv1_wval(w1, g, m, k);
                float hf = __bfloat162float(__float2bfloat16(v));
                hv[e] = hf;
                lv[e] = v - hf;
            }
            hi[jp] = packbf(hv[0], hv[1]);
            lo[jp] = packbf(lv[0], lv[1]);
        }
        int b0 = WS_WA + idx * 8;
        #pragma unroll
        for (int i = 0; i < 4; ++i) { wsu[b0 + i] = hi[i]; wsu[b0 + 4 + i] = lo[i]; }
    }

    // group-max weights [g][o][k]
    for (int idx = tid; idx < 576; idx += 256) {
        int g = idx / 144, rem = idx % 144, o = rem / 9, k = rem % 9;
        ws[WS_WGC + idx] = w1[o * 420 + g * 9 + k];
    }
    for (int idx = tid; idx < 256; idx += 256) {
        int o = idx / 16, i = idx % 16;
        ws[WS_WC2 + idx] = w2[o * 144 + i * 9 + 4];
    }
    if (tid < 16) {
        float sc = gamma[tid] * rsqrtf(var[tid] + 1e-5f);
        ws[WS_SC + tid]  = sc;
        ws[WS_OFF + tid] = b2[tid] * sc + beta[tid] - mean[tid] * sc;
    }
}

#define LOAD9(dst, cb) do {                              \
    const float* r0_ = (cb) + (size_t)hmc * Ww + w;      \
    const float* r1_ = (cb) + (size_t)h   * Ww + w;      \
    const float* r2_ = (cb) + (size_t)hpc * Ww + w;      \
    dst[0] = r0_[offm]; dst[1] = r0_[0]; dst[2] = r0_[offp]; \
    dst[3] = r1_[offm]; dst[4] = r1_[0]; dst[5] = r1_[offp]; \
    dst[6] = r2_[offm]; dst[7] = r2_[0]; dst[8] = r2_[offp]; \
} while (0)

__global__ __launch_bounds__(256, 3) void revo_kernel(
    const float* __restrict__ in,
    const float* __restrict__ b1,
    const float* __restrict__ w3, const float* __restrict__ b3,
    const float* __restrict__ ws,
    float* __restrict__ out)
{
    const int tid  = threadIdx.x;
    const int g    = __builtin_amdgcn_readfirstlane(tid >> 6);
    const int l    = tid & 63;

    const int bid     = blockIdx.x;
    const int logical = ((bid & 7) << 8) + (bid >> 3);  // XCD-chunked
    const int wseg = logical & 3;
    const int h    = (logical >> 2) & (Hh - 1);
    const int b    = logical >> 10;
    const int w    = wseg * 64 + l;

    // 48 KB union. Per group g: slab = 768 uint4 (64 px rows x 12 slots).
    // lds_y[g] (64 px x 20 f32) aliases the head of slab g (written only
    // after wave g finished all slab reads; slab g is private to wave g).
    __shared__ uint4 lds_raw[3072];
    uint4* slab  = &lds_raw[g * 768];
    float* ldsYg = (float*)&lds_raw[g * 768];

    const float* base = in + (size_t)b * Cch * HW;

    const bool okm = (w > 0);
    const bool okp = (w < Ww - 1);
    const int offm = okm ? -1 : 0;
    const int offp = okp ?  1 : 0;

    const int hm = h - 1, hp = h + 1;
    const bool okhm = (hm >= 0), okhp = (hp < Hh);
    const int hmc = okhm ? hm : 0;
    const int hpc = okhp ? hp : Hh - 1;

    // ================= phase A: feature generation (pixel = lane) ==========
    float p[9], pn[9];
    float gmax[9];
    unsigned buf[12];

    const float* cb0 = base + (size_t)(g * 16) * HW;
    LOAD9(p, cb0);

    #pragma unroll
    for (int cc = 0; cc < 16; ++cc) {
        if (cc < 15) {
            LOAD9(pn, cb0 + (size_t)(cc + 1) * HW);
        }

        float q[9];
        q[0] = (okhm && okm) ? p[0] : 0.0f;
        q[1] =  okhm         ? p[1] : 0.0f;
        q[2] = (okhm && okp) ? p[2] : 0.0f;
        q[3] =  okm          ? p[3] : 0.0f;
        q[4] =  p[4];
        q[5] =  okp          ? p[5] : 0.0f;
        q[6] = (okhp && okm) ? p[6] : 0.0f;
        q[7] =  okhp         ? p[7] : 0.0f;
        q[8] = (okhp && okp) ? p[8] : 0.0f;

        float mkh0 = fmaxf(fmaxf(q[0], q[3]), q[6]);
        float mkh1 = fmaxf(fmaxf(q[1], q[4]), q[7]);
        float mkh2 = fmaxf(fmaxf(q[2], q[5]), q[8]);
        float mkw0 = fmaxf(fmaxf(q[0], q[1]), q[2]);
        float mkw1 = fmaxf(fmaxf(q[3], q[4]), q[5]);
        float mkw2 = fmaxf(fmaxf(q[6], q[7]), q[8]);

        if (cc == 0) {
            #pragma unroll
            for (int k = 0; k < 9; ++k) gmax[k] = q[k];
        } else {
            #pragma unroll
            for (int k = 0; k < 9; ++k) gmax[k] = fmaxf(gmax[k], q[k]);
        }

        buf[(cc & 3) * 3 + 0] = packbf(mkh0, mkh1);
        buf[(cc & 3) * 3 + 1] = packbf(mkh2, mkw0);
        buf[(cc & 3) * 3 + 2] = packbf(mkw1, mkw2);

        if ((cc & 3) == 3) {                     // flush 4 channels = 3 slots
            int j = cc >> 2;
            uint4 v0; v0.x = buf[0]; v0.y = buf[1];  v0.z = buf[2];  v0.w = buf[3];
            uint4 v1; v1.x = buf[4]; v1.y = buf[5];  v1.z = buf[6];  v1.w = buf[7];
            uint4 v2; v2.x = buf[8]; v2.y = buf[9];  v2.z = buf[10]; v2.w = buf[11];
            slab[l * 12 + ((3 * j + 0) ^ (l & 3))] = v0;
            slab[l * 12 + ((3 * j + 1) ^ (l & 3))] = v1;
            slab[l * 12 + ((3 * j + 2) ^ (l & 3))] = v2;
        }

        #pragma unroll
        for (int k = 0; k < 9; ++k) p[k] = pn[k];
    }

    // ================= phase B: MFMA over own slab (no barrier) =============
    {
        const uint4* wa = (const uint4*)ws;      // WS_WA == 0
        uint4 Ahi[3], Alo[3];
        #pragma unroll
        for (int s = 0; s < 3; ++s) {
            int ix = ((g * 3 + s) * 64 + l) * 2;
            Ahi[s] = wa[ix];
            Alo[s] = wa[ix + 1];
        }

        f32x4 acc[4];
        #pragma unroll
        for (int t = 0; t < 4; ++t) acc[t] = (f32x4){0.f, 0.f, 0.f, 0.f};

        const int ln = l & 15, half = l >> 4;
        #pragma unroll
        for (int s = 0; s < 3; ++s) {
            #pragma unroll
            for (int t = 0; t < 4; ++t) {
                uint4 bv = slab[(16 * t + ln) * 12 + ((4 * s + half) ^ (ln & 3))];
                acc[t] = __builtin_amdgcn_mfma_f32_16x16x32_bf16(
                    __builtin_bit_cast(bf16x8, Ahi[s]),
                    __builtin_bit_cast(bf16x8, bv), acc[t], 0, 0, 0);
                acc[t] = __builtin_amdgcn_mfma_f32_16x16x32_bf16(
                    __builtin_bit_cast(bf16x8, Alo[s]),
                    __builtin_bit_cast(bf16x8, bv), acc[t], 0, 0, 0);
            }
        }

        // slab reads done -> safe to overwrite head with lds_y
        asm volatile("s_waitcnt lgkmcnt(0)" ::: "memory");
        __builtin_amdgcn_sched_barrier(0);

        // D: col(lane&15)=pixel-in-tile, row((lane>>4)*4+r)=output o
        #pragma unroll
        for (int t = 0; t < 4; ++t)
            *(f32x4*)&ldsYg[(16 * t + ln) * 20 + half * 4] = acc[t];
    }

    // group-max contribution (exact f32), same thread still holds gmax[9]
    {
        const float* wgc = ws + WS_WGC + g * 144;
        #pragma unroll
        for (int o = 0; o < 16; ++o) {
            float term = 0.0f;
            #pragma unroll
            for (int k = 0; k < 9; ++k)
                term = fmaf(wgc[o * 9 + k], gmax[k], term);
            atomicAdd(&ldsYg[l * 20 + o], term);
        }
    }
    __syncthreads();

    // ================= reduce partials + epilogue (pixel = lane) ============
    float feat[16];
    {
        f32x4 rr[4];
        #pragma unroll
        for (int r = 0; r < 4; ++r) {
            rr[r] = (f32x4){0.f, 0.f, 0.f, 0.f};
            #pragma unroll
            for (int gp = 0; gp < 4; ++gp)
                rr[r] += *(const f32x4*)&((const float*)&lds_raw[gp * 768])[l * 20 + 4 * r];
        }
        #pragma unroll
        for (int o = 0; o < 16; ++o)
            feat[o] = mishf(rr[o >> 2][o & 3] + b1[o]);
    }

    // conv2 center tap + folded BN + mish gate
    float feat2[16];
    {
        const float* wc2 = ws + WS_WC2;
        const float* sc  = ws + WS_SC;
        const float* off = ws + WS_OFF;
        #pragma unroll
        for (int o = 0; o < 16; ++o) {
            float acc = 0.0f;
            #pragma unroll
            for (int i = 0; i < 16; ++i)
                acc = fmaf(wc2[o * 16 + i], feat[i], acc);
            feat2[o] = feat[o] * mishf(acc * sc[o] + off[o]);
        }
    }

    // conv3 (this group's 9 logits) + softmax
    float att[9];
    {
        float mx = -1e30f;
        #pragma unroll
        for (int k = 0; k < 9; ++k) {
            float acc = b3[g * 9 + k];
            const float* r = w3 + (g * 9 + k) * 16;
            #pragma unroll
            for (int i = 0; i < 16; ++i)
                acc = fmaf(r[i], feat2[i], acc);
            att[k] = acc;
            mx = fmaxf(mx, acc);
        }
        float s = 0.0f;
        #pragma unroll
        for (int k = 0; k < 9; ++k) { att[k] = __expf(att[k] - mx); s += att[k]; }
        float inv = __fdividef(1.0f, s);
        #pragma unroll
        for (int k = 0; k < 9; ++k) att[k] *= inv;
    }

    // aggregation over this group's 16 channels (1-ahead pipeline)
    float* ob = out + (((size_t)b * Cch) * Hh + h) * Ww + w;
    LOAD9(p, cb0);
    for (int gc = 0; gc < 16; ++gc) {
        if (gc < 15) {
            LOAD9(pn, cb0 + (size_t)(gc + 1) * HW);
        }
        float acc = 0.0f;
        acc = fmaf((okhm && okm) ? p[0] : 0.0f, att[0], acc);
        acc = fmaf( okhm         ? p[1] : 0.0f, att[1], acc);
        acc = fmaf((okhm && okp) ? p[2] : 0.0f, att[2], acc);
        acc = fmaf( okm          ? p[3] : 0.0f, att[3], acc);
        acc = fmaf( p[4],                       att[4], acc);
        acc = fmaf( okp          ? p[5] : 0.0f, att[5], acc);
        acc = fmaf((okhp && okm) ? p[6] : 0.0f, att[6], acc);
        acc = fmaf( okhp         ? p[7] : 0.0f, att[7], acc);
        acc = fmaf((okhp && okp) ? p[8] : 0.0f, att[8], acc);
        ob[(size_t)(g * 16 + gc) * HW] = acc;

        #pragma unroll
        for (int k = 0; k < 9; ++k) p[k] = pn[k];
    }
}

extern "C" void kernel_launch(void* const* d_in, const int* in_sizes, int n_in,
                              void* d_out, int out_size, void* d_ws, size_t ws_size,
                              hipStream_t stream) {
    const float* in    = (const float*)d_in[0];
    const float* w1    = (const float*)d_in[1];
    const float* b1    = (const float*)d_in[2];
    const float* w2    = (const float*)d_in[3];
    const float* b2    = (const float*)d_in[4];
    const float* w3    = (const float*)d_in[5];
    const float* b3    = (const float*)d_in[6];
    const float* gamma = (const float*)d_in[7];
    const float* beta  = (const float*)d_in[8];
    const float* mean  = (const float*)d_in[9];
    const float* var   = (const float*)d_in[10];
    float* out = (float*)d_out;
    float* ws  = (float*)d_ws;

    hipLaunchKernelGGL(prep_kernel, dim3(1), dim3(256), 0, stream,
                       w1, w2, b2, gamma, beta, mean, var, ws);

    hipLaunchKernelGGL(revo_kernel, dim3(2048), dim3(256), 0, stream,
                       in, b1, w3, b3, ws, out);
}

// Round 6
// 112.650 us; speedup vs baseline: 1.1448x; 1.1448x over previous
//
#include <hip/hip_runtime.h>
#include <hip/hip_bf16.h>
#include <math.h>

#define Cch 64
#define Hh  256
#define Ww  256
#define HW  (Hh * Ww)

// ws layout: u32 [0,8192) = A-frags [4 g][4 s][64 lane][8 u32] (hi 4, lo 4)
// f32 idx 8192.. : conv2 taps, BN scale/offset
#define WS_WC2  8192     // [16][16] f32 conv2 center taps
#define WS_SC   8448     // [16] BN scale
#define WS_OFF  8464     // [16] BN offset (incl conv2 bias)

// stage: per group 16ch x 3rows x 67(stride; 66 used) f32
#define SROW 67
#define SCH  201        // 3*67
#define SGRP 3216       // 16*201
#define LDSY 12864      // 4*SGRP ; lds_y = [4][64][20] f32 after this
#define LDS_TOT (12864 + 5120)

typedef __attribute__((ext_vector_type(8))) short bf16x8;
typedef __attribute__((ext_vector_type(4))) float f32x4;

__device__ __forceinline__ float mishf(float x) {
    float e  = __expf(fminf(x, 15.0f));
    float n  = 1.0f + e;
    float n2 = n * n;
    float t  = __fdividef(n2 - 1.0f, n2 + 1.0f);
    return x > 15.0f ? x : x * t;
}

__device__ __forceinline__ unsigned packbf(float a, float b) {
    unsigned short ua = __builtin_bit_cast(unsigned short, __float2bfloat16(a));
    unsigned short ub = __builtin_bit_cast(unsigned short, __float2bfloat16(b));
    return (unsigned)ua | ((unsigned)ub << 16);
}

// conv1 weight, k-layout k = 8*cc + j:
// j<3: m_kh(kw=j) of channel g*16+cc ; j in 3..5: m_kw(kh=j-3)
// j==6: group-max weight for tap cc (only cc<9) ; j==7: zero pad
__device__ __forceinline__ float conv1_wval(const float* w1, int g, int m,
                                            int cc, int j) {
    int c = g * 16 + cc;
    if (j < 3)  return w1[m * 420 + 36 + c * 3 + j];
    if (j < 6)  return w1[m * 420 + 228 + c * 3 + (j - 3)];
    if (j == 6) return (cc < 9) ? w1[m * 420 + g * 9 + cc] : 0.0f;
    return 0.0f;
}

__global__ __launch_bounds__(256) void prep_kernel(
    const float* __restrict__ w1, const float* __restrict__ w2,
    const float* __restrict__ b2,
    const float* __restrict__ gamma, const float* __restrict__ beta,
    const float* __restrict__ mean,  const float* __restrict__ var,
    float* __restrict__ ws)
{
    unsigned* wsu = (unsigned*)ws;
    const int tid = threadIdx.x;

    // A-frags: lane holds A[m=lane&15][k=8*cc+j], cc=4s+(lane>>4), j=0..7
    for (int idx = tid; idx < 1024; idx += 256) {
        int g = idx >> 8, s = (idx >> 6) & 3, lane = idx & 63;
        int m = lane & 15, half = lane >> 4;
        int cc = 4 * s + half;
        unsigned hi[4], lo[4];
        #pragma unroll
        for (int jp = 0; jp < 4; ++jp) {
            float hv[2], lv[2];
            #pragma unroll
            for (int e = 0; e < 2; ++e) {
                float v  = conv1_wval(w1, g, m, cc, jp * 2 + e);
                float hf = __bfloat162float(__float2bfloat16(v));
                hv[e] = hf;
                lv[e] = v - hf;
            }
            hi[jp] = packbf(hv[0], hv[1]);
            lo[jp] = packbf(lv[0], lv[1]);
        }
        int b0 = idx * 8;
        #pragma unroll
        for (int i = 0; i < 4; ++i) { wsu[b0 + i] = hi[i]; wsu[b0 + 4 + i] = lo[i]; }
    }

    for (int idx = tid; idx < 256; idx += 256) {
        int o = idx / 16, i = idx % 16;
        ws[WS_WC2 + idx] = w2[o * 144 + i * 9 + 4];
    }
    if (tid < 16) {
        float sc = gamma[tid] * rsqrtf(var[tid] + 1e-5f);
        ws[WS_SC + tid]  = sc;
        ws[WS_OFF + tid] = b2[tid] * sc + beta[tid] - mean[tid] * sc;
    }
}

__global__ __launch_bounds__(256) void revo_kernel(
    const float* __restrict__ in,
    const float* __restrict__ b1,
    const float* __restrict__ w3, const float* __restrict__ b3,
    const float* __restrict__ ws,
    float* __restrict__ out)
{
    const int tid  = threadIdx.x;
    const int g    = __builtin_amdgcn_readfirstlane(tid >> 6);
    const int l    = tid & 63;

    const int bid     = blockIdx.x;
    const int logical = ((bid & 7) << 8) + (bid >> 3);  // XCD-chunked
    const int wseg = logical & 3;
    const int h    = (logical >> 2) & (Hh - 1);
    const int b    = logical >> 10;
    const int wbase = wseg * 64;
    const int w     = wbase + l;

    __shared__ float lds[LDS_TOT];
    float* stageg = lds + g * SGRP;
    float* ldsy   = lds + LDSY;     // [4][64][20]

    const float* base = in + ((size_t)b * Cch + g * 16) * HW;

    // ============ staging: 16 ch x 3 rows x 66 cols, zero-padded ============
    {
        #pragma unroll 6
        for (int it = 0; it < 48; ++it) {
            int c = it / 3, r = it % 3;
            int hr = h + r - 1;
            float v = 0.0f, vh = 0.0f;
            if (hr >= 0 && hr < Hh) {                  // uniform branch
                const float* rowp = base + (size_t)c * HW + (size_t)hr * Ww;
                v = rowp[wbase + l];                   // cols wbase..wbase+63
                if (l == 0 && wseg > 0)  vh = rowp[wbase - 1];
                if (l == 63 && wseg < 3) vh = rowp[wbase + 64];
            }
            stageg[c * SCH + r * SROW + 1 + l] = v;
            if (l == 0)  stageg[c * SCH + r * SROW]      = vh;
            if (l == 63) stageg[c * SCH + r * SROW + 65] = vh;
        }
    }
    // stage region is private to this wave; DS ops are in-order per wave ->
    // no barrier needed before reading it back.

    // ============ conv1 via MFMA, B-frags built in-register =================
    const int ln = l & 15, half = l >> 4;
    f32x4 acc[4];
    #pragma unroll
    for (int t = 0; t < 4; ++t) acc[t] = (f32x4){0.f, 0.f, 0.f, 0.f};

    {
        const uint4* wa = (const uint4*)ws;
        uint4 Ahi[4], Alo[4];
        #pragma unroll
        for (int s = 0; s < 4; ++s) {
            int ix = ((g * 4 + s) * 64 + l) * 2;
            Ahi[s] = wa[ix];
            Alo[s] = wa[ix + 1];
        }

        #pragma unroll
        for (int s = 0; s < 4; ++s) {
            const int cc = 4 * s + half;          // this lane's channel
            const float* chp = stageg + cc * SCH;
            const bool hasgc = (cc < 9);          // uniform per 16-lane group
            const int rp = cc / 3, dp = cc % 3;   // gc tap decode

            #pragma unroll
            for (int t = 0; t < 4; ++t) {
                const int p = 16 * t + ln;        // pixel for this B column
                float a0 = chp[p],           a1 = chp[p + 1],       a2 = chp[p + 2];
                float b0 = chp[SROW + p],    b1v = chp[SROW + p + 1], b2v = chp[SROW + p + 2];
                float c0 = chp[2*SROW + p],  c1 = chp[2*SROW + p + 1], c2 = chp[2*SROW + p + 2];

                float mkh0 = fmaxf(fmaxf(a0, b0), c0);
                float mkh1 = fmaxf(fmaxf(a1, b1v), c1);
                float mkh2 = fmaxf(fmaxf(a2, b2v), c2);
                float mkw0 = fmaxf(fmaxf(a0, a1), a2);
                float mkw1 = fmaxf(fmaxf(b0, b1v), b2v);
                float mkw2 = fmaxf(fmaxf(c0, c1), c2);

                float gv = 0.0f;
                if (hasgc) {                      // 16-channel max of tap cc
                    const float* gp2 = stageg + rp * SROW + dp + p;
                    gv = gp2[0];
                    #pragma unroll
                    for (int c2i = 1; c2i < 16; ++c2i)
                        gv = fmaxf(gv, gp2[c2i * SCH]);
                }

                uint4 bv;
                bv.x = packbf(mkh0, mkh1);
                bv.y = packbf(mkh2, mkw0);
                bv.z = packbf(mkw1, mkw2);
                bv.w = packbf(gv, 0.0f);

                acc[t] = __builtin_amdgcn_mfma_f32_16x16x32_bf16(
                    __builtin_bit_cast(bf16x8, Ahi[s]),
                    __builtin_bit_cast(bf16x8, bv), acc[t], 0, 0, 0);
                acc[t] = __builtin_amdgcn_mfma_f32_16x16x32_bf16(
                    __builtin_bit_cast(bf16x8, Alo[s]),
                    __builtin_bit_cast(bf16x8, bv), acc[t], 0, 0, 0);
            }
        }
    }

    // write partial y: D row(4*half+j)=output o, col(ln)=pixel-in-tile
    #pragma unroll
    for (int t = 0; t < 4; ++t)
        *(f32x4*)&ldsy[(g * 64 + 16 * t + ln) * 20 + 4 * half] = acc[t];
    __syncthreads();

    // ============ reduce partials + epilogue (pixel = lane) =================
    float feat[16];
    {
        #pragma unroll
        for (int r4 = 0; r4 < 4; ++r4) {
            f32x4 rr = (f32x4){0.f, 0.f, 0.f, 0.f};
            #pragma unroll
            for (int gp = 0; gp < 4; ++gp)
                rr += *(const f32x4*)&ldsy[(gp * 64 + l) * 20 + 4 * r4];
            #pragma unroll
            for (int j = 0; j < 4; ++j)
                feat[4 * r4 + j] = rr[j];
        }
        #pragma unroll
        for (int o = 0; o < 16; ++o) feat[o] = mishf(feat[o] + b1[o]);
    }

    float feat2[16];
    {
        const float* wc2 = ws + WS_WC2;
        const float* sc  = ws + WS_SC;
        const float* off = ws + WS_OFF;
        #pragma unroll
        for (int o = 0; o < 16; ++o) {
            float acc2 = 0.0f;
            #pragma unroll
            for (int i = 0; i < 16; ++i)
                acc2 = fmaf(wc2[o * 16 + i], feat[i], acc2);
            feat2[o] = feat[o] * mishf(acc2 * sc[o] + off[o]);
        }
    }

    float att[9];
    {
        float mx = -1e30f;
        #pragma unroll
        for (int k = 0; k < 9; ++k) {
            float acc2 = b3[g * 9 + k];
            const float* r = w3 + (g * 9 + k) * 16;
            #pragma unroll
            for (int i = 0; i < 16; ++i)
                acc2 = fmaf(r[i], feat2[i], acc2);
            att[k] = acc2;
            mx = fmaxf(mx, acc2);
        }
        float s = 0.0f;
        #pragma unroll
        for (int k = 0; k < 9; ++k) { att[k] = __expf(att[k] - mx); s += att[k]; }
        float inv = __fdividef(1.0f, s);
        #pragma unroll
        for (int k = 0; k < 9; ++k) att[k] *= inv;
    }

    // ============ aggregation from staged taps ==============================
    float* ob = out + (((size_t)b * Cch + g * 16) * Hh + h) * Ww + w;
    #pragma unroll 4
    for (int c = 0; c < 16; ++c) {
        const float* chp = stageg + c * SCH;
        float a0 = chp[l],          a1 = chp[l + 1],          a2 = chp[l + 2];
        float b0 = chp[SROW + l],   b1v = chp[SROW + l + 1],  b2v = chp[SROW + l + 2];
        float c0 = chp[2*SROW + l], c1 = chp[2*SROW + l + 1], c2 = chp[2*SROW + l + 2];
        float acc2 = 0.0f;
        acc2 = fmaf(a0,  att[0], acc2);
        acc2 = fmaf(a1,  att[1], acc2);
        acc2 = fmaf(a2,  att[2], acc2);
        acc2 = fmaf(b0,  att[3], acc2);
        acc2 = fmaf(b1v, att[4], acc2);
        acc2 = fmaf(b2v, att[5], acc2);
        acc2 = fmaf(c0,  att[6], acc2);
        acc2 = fmaf(c1,  att[7], acc2);
        acc2 = fmaf(c2,  att[8], acc2);
        ob[(size_t)c * HW] = acc2;
    }
}

extern "C" void kernel_launch(void* const* d_in, const int* in_sizes, int n_in,
                              void* d_out, int out_size, void* d_ws, size_t ws_size,
                              hipStream_t stream) {
    const float* in    = (const float*)d_in[0];
    const float* w1    = (const float*)d_in[1];
    const float* b1    = (const float*)d_in[2];
    const float* w2    = (const float*)d_in[3];
    const float* b2    = (const float*)d_in[4];
    const float* w3    = (const float*)d_in[5];
    const float* b3    = (const float*)d_in[6];
    const float* gamma = (const float*)d_in[7];
    const float* beta  = (const float*)d_in[8];
    const float* mean  = (const float*)d_in[9];
    const float* var   = (const float*)d_in[10];
    float* out = (float*)d_out;
    float* ws  = (float*)d_ws;

    hipLaunchKernelGGL(prep_kernel, dim3(1), dim3(256), 0, stream,
                       w1, w2, b2, gamma, beta, mean, var, ws);

    hipLaunchKernelGGL(revo_kernel, dim3(2048), dim3(256), 0, stream,
                       in, b1, w3, b3, ws, out);
}